// Round 4
// baseline (233.506 us; speedup 1.0000x reference)
//
#include <hip/hip_runtime.h>
#include <math.h>

// Problem constants (from reference)
#define BB 16
#define VV 6890
#define NFF 13776
#define HH 512
#define WW 512
// SIGMA = 1e-4 -> 1/SIGMA = 1e4

typedef float nf4 __attribute__((ext_vector_type(4)));  // native vec4 for nontemporal ld/st
typedef int   ni4 __attribute__((ext_vector_type(4)));

// ---------------------------------------------------------------------------
// Stage 1: per-(batch, vertex-half) vertex normals entirely in LDS.
// Each block sweeps ALL faces, computes the face normal (2x redundant across
// halves -- cheap), and LDS-atomicAdds into its half's accumulator. Then
// normalizes and writes vn4 coalesced. No global atomics, no CSR, no memset.
// ---------------------------------------------------------------------------
#define GEOT 1024
#define NHALF 2
#define VHALF ((VV + NHALF - 1) / NHALF)  // 3445

__global__ __launch_bounds__(GEOT) void k_vn_half(const float* __restrict__ verts,
                                                  const int* __restrict__ faces,
                                                  float4* __restrict__ vn4) {
    __shared__ float sx[VHALF], sy[VHALF], sz[VHALF];  // 3*3445*4 = 41.3 KB
    int blk = blockIdx.x;
    int b    = blk >> 1;   // NHALF == 2
    int half = blk & 1;
    int lo = half * VHALF;
    int hi = lo + VHALF; if (hi > VV) hi = VV;
    int nloc = hi - lo;
    int t = threadIdx.x;

    for (int v = t; v < nloc; v += GEOT) { sx[v] = 0.f; sy[v] = 0.f; sz[v] = 0.f; }
    __syncthreads();

    const float* vb = verts + (size_t)b * (VV * 3);
    for (int f = t; f < NFF; f += GEOT) {
        int i0 = faces[3 * f + 0];
        int i1 = faces[3 * f + 1];
        int i2 = faces[3 * f + 2];
        float ax = vb[3 * i0 + 0], ay = vb[3 * i0 + 1], az = vb[3 * i0 + 2];
        float bx = vb[3 * i1 + 0], by = vb[3 * i1 + 1], bz = vb[3 * i1 + 2];
        float cx = vb[3 * i2 + 0], cy = vb[3 * i2 + 1], cz = vb[3 * i2 + 2];
        float e1x = bx - ax, e1y = by - ay, e1z = bz - az;
        float e2x = cx - ax, e2y = cy - ay, e2z = cz - az;
        float nx = e1y * e2z - e1z * e2y;
        float ny = e1z * e2x - e1x * e2z;
        float nz = e1x * e2y - e1y * e2x;
        int j0 = i0 - lo, j1 = i1 - lo, j2 = i2 - lo;
        if ((unsigned)j0 < (unsigned)nloc) {
            atomicAdd(&sx[j0], nx); atomicAdd(&sy[j0], ny); atomicAdd(&sz[j0], nz);
        }
        if ((unsigned)j1 < (unsigned)nloc) {
            atomicAdd(&sx[j1], nx); atomicAdd(&sy[j1], ny); atomicAdd(&sz[j1], nz);
        }
        if ((unsigned)j2 < (unsigned)nloc) {
            atomicAdd(&sx[j2], nx); atomicAdd(&sy[j2], ny); atomicAdd(&sz[j2], nz);
        }
    }
    __syncthreads();

    float4* vnb = vn4 + (size_t)b * VV;
    for (int v = t; v < nloc; v += GEOT) {
        float x = sx[v], y = sy[v], z = sz[v];
        float inv = 1.0f / fmaxf(sqrtf(x * x + y * y + z * z), 1e-6f);
        float4 o; o.x = x * inv; o.y = y * inv; o.z = z * inv; o.w = 0.f;
        vnb[lo + v] = o;
    }
}

// ---------------------------------------------------------------------------
// Stage 2: face_attr_sum[b,f] = sum of the 3 normalized vertex normals
// ---------------------------------------------------------------------------
__global__ __launch_bounds__(256) void k_face_sum(const float4* __restrict__ vn4,
                                                  const int* __restrict__ faces,
                                                  float4* __restrict__ fas4) {
    int i = blockIdx.x * 256 + threadIdx.x;
    if (i >= BB * NFF) return;
    int b = i / NFF;
    int f = i - b * NFF;
    int i0 = faces[3 * f + 0], i1 = faces[3 * f + 1], i2 = faces[3 * f + 2];
    const float4* vnb = vn4 + (size_t)b * VV;
    float4 a = vnb[i0], bb = vnb[i1], cc = vnb[i2];
    float4 o;
    o.x = a.x + bb.x + cc.x;
    o.y = a.y + bb.y + cc.y;
    o.z = a.z + bb.z + cc.z;
    o.w = 0.f;
    fas4[i] = o;
}

// ---------------------------------------------------------------------------
// Stage 3: per-pixel gather + normalize + alpha. 4 pixels per thread.
// Streaming inputs/outputs nontemporal so the fas4 gather table stays in L2.
// ---------------------------------------------------------------------------
__device__ __forceinline__ nf4 pixel_one(int f, float d, const float4* __restrict__ fasb) {
    float px = 0.f, py = 0.f, pz = 0.f, prob = 0.f;
    if (f >= 0) {
        int fc = f < (NFF - 1) ? f : (NFF - 1);
        float4 p = fasb[fc];
        px = p.x; py = p.y; pz = p.z;
        prob = __builtin_amdgcn_rcpf(1.0f + __expf(d * 1.0e4f));  // sigmoid(-d/SIGMA)
    }
    float n2 = px * px + py * py + pz * pz;
    float inv = __builtin_amdgcn_rcpf(fmaxf(sqrtf(n2), 1e-12f));
    float hitadd = (n2 > 0.f) ? 0.f : 1.0f;
    nf4 o;
    o.x = px * inv + hitadd;
    o.y = py * inv + hitadd;
    o.z = pz * inv + hitadd;
    o.w = 1.0f - prob;
    return o;
}

__global__ __launch_bounds__(256) void k_pixel(const int* __restrict__ p2f,
                                               const float* __restrict__ dists,
                                               const float4* __restrict__ fas4,
                                               nf4* __restrict__ out) {
    int i = (blockIdx.x * 256 + threadIdx.x) * 4;
    if (i >= BB * HH * WW) return;
    int b = i >> 18;  // H*W = 2^18; quad never crosses batch boundary (4 | 2^18)
    ni4 ff = __builtin_nontemporal_load((const ni4*)(p2f + i));
    nf4 dd = __builtin_nontemporal_load((const nf4*)(dists + i));
    const float4* fasb = fas4 + (size_t)b * NFF;
    nf4 o0 = pixel_one(ff.x, dd.x, fasb);
    nf4 o1 = pixel_one(ff.y, dd.y, fasb);
    nf4 o2 = pixel_one(ff.z, dd.z, fasb);
    nf4 o3 = pixel_one(ff.w, dd.w, fasb);
    __builtin_nontemporal_store(o0, &out[i]);
    __builtin_nontemporal_store(o1, &out[i + 1]);
    __builtin_nontemporal_store(o2, &out[i + 2]);
    __builtin_nontemporal_store(o3, &out[i + 3]);
}

// ---------------------------------------------------------------------------
extern "C" void kernel_launch(void* const* d_in, const int* in_sizes, int n_in,
                              void* d_out, int out_size, void* d_ws, size_t ws_size,
                              hipStream_t stream) {
    const float* verts = (const float*)d_in[0];
    // d_in[1] = zbuf: dead in the reference's returned value -> never read
    const float* dists = (const float*)d_in[2];
    const int* faces   = (const int*)d_in[3];
    const int* p2f     = (const int*)d_in[4];

    // Workspace layout (16B-aligned chunks)
    char* w = (char*)d_ws;
    float4* vn4  = (float4*)w;  w += (size_t)BB * VV * 16;    // 1.76 MB
    float4* fas4 = (float4*)w;  w += (size_t)BB * NFF * 16;   // 3.53 MB

    int nbf = BB * NFF;  // 220416

    k_vn_half<<<BB * NHALF, GEOT, 0, stream>>>(verts, faces, vn4);
    k_face_sum<<<(nbf + 255) / 256, 256, 0, stream>>>(vn4, faces, fas4);

    int npix = BB * HH * WW;  // 4,194,304
    k_pixel<<<npix / 4 / 256, 256, 0, stream>>>(p2f, dists, fas4, (nf4*)d_out);
}